// Round 8
// baseline (1684.795 us; speedup 1.0000x reference)
//
#include <hip/hip_runtime.h>

typedef __attribute__((ext_vector_type(8))) short short8;
typedef __attribute__((ext_vector_type(4))) float f32x4;
typedef __attribute__((ext_vector_type(4))) unsigned int u32x4;

// ---------- helpers ----------
__device__ __forceinline__ unsigned short f2bu(float x) {
  unsigned int u = __float_as_uint(x);
  u += 0x7fffu + ((u >> 16) & 1u);
  return (unsigned short)(u >> 16);
}
__device__ __forceinline__ unsigned int pk2(float a, float b) {
  return (unsigned int)f2bu(a) | ((unsigned int)f2bu(b) << 16);
}
__device__ __forceinline__ void gload_lds16(const void* g, void* l) {
  __builtin_amdgcn_global_load_lds((const __attribute__((address_space(1))) unsigned int*)g,
                                   (__attribute__((address_space(3))) unsigned int*)l, 16, 0, 0);
}
// coherent DMA: aux = sc0|sc1 (CPol GLC=1 | SCC=16) — bypasses stale L1/L2
__device__ __forceinline__ void gload_lds16_coh(const void* g, void* l) {
  __builtin_amdgcn_global_load_lds((const __attribute__((address_space(1))) unsigned int*)g,
                                   (__attribute__((address_space(3))) unsigned int*)l, 16, 0, 17);
}
__device__ __forceinline__ void store4_coh(void* p, unsigned int v) {
  asm volatile("global_store_dword %0, %1, off sc0 sc1" :: "v"(p), "v"(v) : "memory");
}
__device__ __forceinline__ bool ok8(u32x4 a, u32x4 b, int need) {
  return (int)a.x >= need && (int)a.y >= need && (int)a.z >= need && (int)a.w >= need &&
         (int)b.x >= need && (int)b.y >= need && (int)b.z >= need && (int)b.w >= need;
}

// ---------- cast & concat ----------
__global__ void cast_concat_kernel(const float* __restrict__ Mf,
                                   const float* __restrict__ DTf,
                                   const float* __restrict__ Df,
                                   unsigned short* __restrict__ ins) {
  size_t idx = (size_t)blockIdx.x * blockDim.x + threadIdx.x;
  size_t e0 = idx * 8;
  size_t m = e0 >> 10;
  int c = (int)(e0 & 1023);
  const float* src;
  if (c < 256)      src = Mf  + m * 256 + c;
  else if (c < 512) src = DTf + m * 256 + (c - 256);
  else              src = Df  + m * 512 + (c - 512);
  float4 f0 = reinterpret_cast<const float4*>(src)[0];
  float4 f1 = reinterpret_cast<const float4*>(src)[1];
  uint4 o;
  o.x = pk2(f0.x, f0.y); o.y = pk2(f0.z, f0.w);
  o.z = pk2(f1.x, f1.y); o.w = pk2(f1.z, f1.w);
  *reinterpret_cast<uint4*>(ins + e0) = o;
}

__global__ void cast_w_kernel(const float* __restrict__ in, unsigned short* __restrict__ out, int n8) {
  int idx = blockIdx.x * blockDim.x + threadIdx.x;
  if (idx >= n8) return;
  const float* src = in + (size_t)idx * 8;
  float4 f0 = reinterpret_cast<const float4*>(src)[0];
  float4 f1 = reinterpret_cast<const float4*>(src)[1];
  uint4 o;
  o.x = pk2(f0.x, f0.y); o.y = pk2(f0.z, f0.w);
  o.z = pk2(f1.x, f1.y); o.w = pk2(f1.z, f1.w);
  *reinterpret_cast<uint4*>(out + (size_t)idx * 8) = o;
}

// ---------- GEMM (m97 structure, unchanged) ----------
template <int RELU, typename TOUT>
__global__ __launch_bounds__(256) void gemm_bt_kernel(const unsigned short* __restrict__ A,
                                                      const unsigned short* __restrict__ Bt,
                                                      TOUT* __restrict__ C,
                                                      int M, int N, int K) {
  __shared__ unsigned short As[128 * 32];
  __shared__ unsigned short Bs[128 * 32];
  const int tid = threadIdx.x;
  const int l = tid & 63, w = tid >> 6;
  const int lr = l & 15, lg = l >> 4;
  const int wm = w >> 1, wn = w & 1;
  const int tiles_n = N >> 7;
  const int tm = blockIdx.x / tiles_n, tn = blockIdx.x % tiles_n;
  const int bm0 = tm << 7, bn0 = tn << 7;

  f32x4 acc[4][4] = {};

  for (int kt = 0; kt < K; kt += 32) {
#pragma unroll
    for (int i = 0; i < 2; ++i) {
      int ch = tid + (i << 8);
      int row = ch >> 2, cc = ch & 3;
      const unsigned short* ga = A + (size_t)(bm0 + row) * K + kt + cc * 8;
      const unsigned short* gb = Bt + (size_t)(bn0 + row) * K + kt + cc * 8;
      unsigned short* la = As + ((size_t)((i << 8) + (w << 6))) * 8;
      unsigned short* lb = Bs + ((size_t)((i << 8) + (w << 6))) * 8;
      gload_lds16(ga, la);
      gload_lds16(gb, lb);
    }
    __syncthreads();
    short8 af[4], bf[4];
#pragma unroll
    for (int mi = 0; mi < 4; ++mi)
      af[mi] = *reinterpret_cast<const short8*>(As + (wm * 64 + mi * 16 + lr) * 32 + lg * 8);
#pragma unroll
    for (int ni = 0; ni < 4; ++ni)
      bf[ni] = *reinterpret_cast<const short8*>(Bs + (wn * 64 + ni * 16 + lr) * 32 + lg * 8);
#pragma unroll
    for (int mi = 0; mi < 4; ++mi)
#pragma unroll
      for (int ni = 0; ni < 4; ++ni)
        acc[mi][ni] = __builtin_amdgcn_mfma_f32_16x16x32_bf16(af[mi], bf[ni], acc[mi][ni], 0, 0, 0);
    __syncthreads();
  }

#pragma unroll
  for (int mi = 0; mi < 4; ++mi)
#pragma unroll
    for (int ni = 0; ni < 4; ++ni)
#pragma unroll
      for (int r = 0; r < 4; ++r) {
        int row = bm0 + wm * 64 + mi * 16 + lg * 4 + r;
        int col = bn0 + wn * 64 + ni * 16 + lr;
        float v = acc[mi][ni][r];
        if (RELU) v = fmaxf(v, 0.f);
        if constexpr (sizeof(TOUT) == 2) {
          reinterpret_cast<unsigned short*>(C)[(size_t)row * N + col] = f2bu(v);
        } else {
          C[(size_t)row * N + col] = v;
        }
      }
}

// ---------- recurrence: dual-stream, 8-way j-split, fence-free ----------
// 64 blocks = 8 pairs (p) x 8 j-eighths (q); bid = q*8+p puts a pair's 8
// producers on one XCD (perf hint only). Streams A/B = rows 32p / 32p+16.
// W rows [64q,64q+64) LDS-resident (64KB). x image per group: [8 slices]
// [16 rows][128B], byte = sl*2048 + row*128 + ((2*cl)^((row&7)<<4)).
// Protocol: publish sc0sc1 stores; acks + flag release deferred one half;
// flags prefetched one half early; consumer DMA aux=17 (no fences anywhere).
#define XBUF(S, P) (smem + 65536 + (((S) * 2 + (P)) << 14))

__global__ __launch_bounds__(256)
void recurrence_dual(const float* __restrict__ Whh1,
                     const float* __restrict__ x0f,
                     const float* __restrict__ G,
                     unsigned short* xex,   // [2][16 groups][16KB]
                     int* flags,            // [16 groups][8]
                     float* X, float* Y) {
  __shared__ char smem[131072];
  const int tid = threadIdx.x;
  const int l = tid & 63, wv = tid >> 6;
  const int lr = l & 15, lg = l >> 4;
  const int bid = blockIdx.x;
  const int p = bid & 7, q = bid >> 3;
  const int jcolw = (wv << 4) + lr;
  const int jglob = (q << 6) + jcolw;
  char* Wl = smem;
  char* xexb = (char*)xex;
  const int swa = (lr & 7) << 4;
  const int sww = (jcolw & 7) << 4;
  const char* wbp = Wl + jcolw * 1024;

  // ---- one-time: swizzled W-eighth image ----
  {
    int jj = tid >> 2;
    int kseg = (tid & 3) << 7;
    const float* wr = Whh1 + (size_t)(64 * q + jj) * 512 + kseg;
    int sw = (jj & 7) << 4;
    for (int kk = 0; kk < 128; kk += 8) {
      float4 f0 = reinterpret_cast<const float4*>(wr + kk)[0];
      float4 f1 = reinterpret_cast<const float4*>(wr + kk)[1];
      uint4 o;
      o.x = pk2(f0.x, f0.y); o.y = pk2(f0.z, f0.w);
      o.z = pk2(f1.x, f1.y); o.w = pk2(f1.z, f1.w);
      *reinterpret_cast<uint4*>(Wl + jj * 1024 + ((2 * (kseg + kk)) ^ sw)) = o;
    }
  }
  // ---- one-time: x_0 images for both streams ----
#pragma unroll
  for (int s = 0; s < 2; ++s) {
    int r0s = (p << 5) + (s << 4);
    char* dst = XBUF(s, 0);
#pragma unroll
    for (int c = 0; c < 4; ++c) {
      int ci = tid + (c << 8);
      int row = ci >> 6;
      int kc = (ci & 63) << 3;
      const float* src = x0f + (size_t)(r0s + row) * 512 + kc;
      float4 f0 = reinterpret_cast<const float4*>(src)[0];
      float4 f1 = reinterpret_cast<const float4*>(src)[1];
      uint4 o;
      o.x = pk2(f0.x, f0.y); o.y = pk2(f0.z, f0.w);
      o.z = pk2(f1.x, f1.y); o.w = pk2(f1.z, f1.w);
      int sl = kc >> 6, cl = kc & 63;
      *reinterpret_cast<uint4*>(dst + sl * 2048 + row * 128 +
                                ((2 * cl) ^ ((row & 7) << 4))) = o;
    }
  }
  __syncthreads();

  int* flagp[2] = {flags + (2 * p) * 8 + q, flags + (2 * p + 1) * 8 + q};
  const int* fb0 = flags + (2 * p) * 8;
  const int* fb1 = flags + (2 * p + 1) * 8;
  int rqs[7];
  {
    int n = 0;
    for (int qq = 0; qq < 8; ++qq)
      if (qq != q) rqs[n++] = qq;
  }
  u32x4 fva0 = {}, fvb0 = {}, fva1 = {}, fvb1 = {};
  const int r0A = p << 5;
  const int r0B = (p << 5) + 16;

#define HALF(S, T, FVA, FVB, FB, FVA2, FVB2, FB2, R0S)                          \
  {                                                                             \
    asm volatile("s_waitcnt vmcnt(4) lgkmcnt(0)" ::: "memory");                 \
    __builtin_amdgcn_sched_barrier(0);                                          \
    __builtin_amdgcn_s_barrier();                                               \
    if (tid == 0) {                                                             \
      if (S == 0) { if ((T) >= 1) store4_coh(flagp[1], (unsigned int)(T)); }    \
      else        { if ((T) < 255) store4_coh(flagp[0], (unsigned int)((T) + 1)); } \
    }                                                                           \
    char* xrd = ((T) & 1) ? XBUF(S, 1) : XBUF(S, 0);                            \
    if ((T) >= 1) {                                                             \
      asm volatile("" : "+v"(FVA), "+v"(FVB));                                  \
      while (!ok8(FVA, FVB, (T))) {                                             \
        asm volatile("global_load_dwordx4 %0, %2, off sc0 sc1\n\t"              \
                     "global_load_dwordx4 %1, %3, off sc0 sc1\n\t"              \
                     "s_waitcnt vmcnt(0)"                                       \
                     : "=v"(FVA), "=v"(FVB)                                     \
                     : "v"(FB), "v"(FB + 4) : "memory");                        \
      }                                                                         \
      const char* xsb = xexb + ((((T) & 1) * 16 + (2 * p + (S))) * 16384);      \
      _Pragma("unroll") for (int m = 0; m < 7; ++m) {                           \
        if ((m & 3) == wv) {                                                    \
          int qq = rqs[m];                                                      \
          const char* s0 = xsb + qq * 2048 + l * 16;                            \
          char* d0 = xrd + qq * 2048;                                           \
          gload_lds16_coh(s0, d0);                                              \
          gload_lds16_coh(s0 + 1024, d0 + 1024);                                \
        }                                                                       \
      }                                                                         \
    }                                                                           \
    asm volatile("global_load_dwordx4 %0, %2, off sc0 sc1\n\t"                  \
                 "global_load_dwordx4 %1, %3, off sc0 sc1"                      \
                 : "=v"(FVA2), "=v"(FVB2)                                       \
                 : "v"(FB2), "v"(FB2 + 4) : "memory");                          \
    float gv0, gv1, gv2, gv3;                                                   \
    {                                                                           \
      const float* Gp = G + ((size_t)(T) * 256 + (R0S) + lg * 4) * 512 + jglob; \
      gv0 = Gp[0]; gv1 = Gp[512]; gv2 = Gp[1024]; gv3 = Gp[1536];               \
    }                                                                           \
    asm volatile("s_waitcnt vmcnt(0)" ::: "memory");                            \
    __builtin_amdgcn_sched_barrier(0);                                          \
    __builtin_amdgcn_s_barrier();                                               \
    f32x4 acc0 = {}, acc1 = {};                                                 \
    {                                                                           \
      const char* xrp = xrd + lr * 128;                                         \
      _Pragma("unroll") for (int kk = 0; kk < 16; kk += 2) {                    \
        short8 a0 = *reinterpret_cast<const short8*>(                           \
            xrp + (kk >> 1) * 2048 + ((lg << 4) ^ swa));                        \
        short8 a1 = *reinterpret_cast<const short8*>(                           \
            xrp + (kk >> 1) * 2048 + ((64 + (lg << 4)) ^ swa));                 \
        short8 w0 = *reinterpret_cast<const short8*>(                           \
            wbp + (((kk << 6) + (lg << 4)) ^ sww));                             \
        short8 w1 = *reinterpret_cast<const short8*>(                           \
            wbp + ((((kk + 1) << 6) + (lg << 4)) ^ sww));                       \
        acc0 = __builtin_amdgcn_mfma_f32_16x16x32_bf16(a0, w0, acc0, 0, 0, 0);  \
        acc1 = __builtin_amdgcn_mfma_f32_16x16x32_bf16(a1, w1, acc1, 0, 0, 0);  \
      }                                                                         \
    }                                                                           \
    f32x4 accs = acc0 + acc1;                                                   \
    float vv0 = fmaxf(gv0 + accs[0], 0.f), vv1 = fmaxf(gv1 + accs[1], 0.f);     \
    float vv2 = fmaxf(gv2 + accs[2], 0.f), vv3 = fmaxf(gv3 + accs[3], 0.f);     \
    if ((T) < 255) {                                                            \
      char* xn = (((T) + 1) & 1) ? XBUF(S, 1) : XBUF(S, 0);                     \
      char* xd = xexb + ((((((T) + 1) & 1)) * 16 + (2 * p + (S))) * 16384) + q * 2048; \
      float vva[4] = {vv0, vv1, vv2, vv3};                                      \
      _Pragma("unroll") for (int r = 0; r < 4; ++r) {                           \
        float vn = __shfl_xor(vva[r], 1);                                       \
        if (!(lr & 1)) {                                                        \
          int row = lg * 4 + r;                                                 \
          int cl = (wv << 4) + lr;                                              \
          int off = row * 128 + ((2 * cl) ^ ((row & 7) << 4));                  \
          unsigned int pv = pk2(vva[r], vn);                                    \
          *reinterpret_cast<unsigned int*>(xn + q * 2048 + off) = pv;           \
          store4_coh(xd + off, pv);                                             \
        }                                                                       \
      }                                                                         \
    }                                                                           \
    {                                                                           \
      float* Xp = X + ((size_t)(T) * 256 + (R0S) + lg * 4) * 512 + jglob;       \
      Xp[0] = vv0; Xp[512] = vv1; Xp[1024] = vv2; Xp[1536] = vv3;               \
    }                                                                           \
    if (q == 7 && wv == 3 && lr == 15) {                                        \
      Y[(T) * 256 + (R0S) + lg * 4 + 0] = vv0;                                  \
      Y[(T) * 256 + (R0S) + lg * 4 + 1] = vv1;                                  \
      Y[(T) * 256 + (R0S) + lg * 4 + 2] = vv2;                                  \
      Y[(T) * 256 + (R0S) + lg * 4 + 3] = vv3;                                  \
    }                                                                           \
  }

  for (int t = 0; t < 256; ++t) {
    HALF(0, t, fva0, fvb0, fb0, fva1, fvb1, fb1, r0A)
    HALF(1, t, fva1, fvb1, fb1, fva0, fvb0, fb0, r0B)
  }
#undef HALF
}

// ---------- launch ----------
extern "C" void kernel_launch(void* const* d_in, const int* in_sizes, int n_in,
                              void* d_out, int out_size, void* d_ws, size_t ws_size,
                              hipStream_t stream) {
  const float* x0   = (const float*)d_in[0];
  const float* Mf   = (const float*)d_in[1];
  const float* DTf  = (const float*)d_in[2];
  const float* Df   = (const float*)d_in[3];
  const float* Wih0 = (const float*)d_in[4];
  const float* Wih1 = (const float*)d_in[6];
  const float* Whh1 = (const float*)d_in[7];

  char* ws = (char*)d_ws;
  unsigned short* ins = (unsigned short*)(ws);
  unsigned short* H   = (unsigned short*)(ws + 134217728ULL);
  unsigned short* w0b = (unsigned short*)(ws + 268435456ULL);
  unsigned short* w1b = (unsigned short*)(ws + 270532608ULL);
  unsigned short* xex = (unsigned short*)(ws + 271581184ULL);  // 512KB
  int* flags          = (int*)(ws + 272105472ULL);             // 128 ints
  float* G = (float*)(ws);   // aliases ins (dead after GEMM1)

  (void)hipMemsetAsync(flags, 0, 8192, stream);
  cast_concat_kernel<<<32768, 256, 0, stream>>>(Mf, DTf, Df, ins);
  cast_w_kernel<<<512, 256, 0, stream>>>(Wih0, w0b, 131072);
  cast_w_kernel<<<256, 256, 0, stream>>>(Wih1, w1b, 65536);

  gemm_bt_kernel<1, unsigned short><<<(65536 / 128) * (1024 / 128), 256, 0, stream>>>(
      ins, w0b, H, 65536, 1024, 1024);
  gemm_bt_kernel<0, float><<<(65536 / 128) * (512 / 128), 256, 0, stream>>>(
      H, w1b, G, 65536, 512, 1024);

  float* X = (float*)d_out;
  float* Y = X + 33554432;
  recurrence_dual<<<64, 256, 0, stream>>>(Whh1, x0, G, xex, flags, X, Y);
}